// Round 7
// baseline (5354.123 us; speedup 1.0000x reference)
//
#include <hip/hip_runtime.h>
#include <hip/hip_bf16.h>
#include <math.h>

// Fused LM-head cross-entropy: loss = mean_valid( logsumexp(x@W^T) - logit[y] )
// N=4096 tokens, H=4096 hidden, V=128000 vocab.
//
// Round 7: collapse 8-phase lockstep to 2 barriers per K-tile. All 24
// ds_read_b128 issued at region head (same buffer -> no intra-tile hazard);
// compiler interleaves counted lgkmcnt with the 64-MFMA stream; barrier
// AFTER the MFMAs (register-only) guarantees read-completion before the
// own-buffer stage of tile t+2; vmcnt(8)+barrier publishes tile t+1.

#define N_ROWS 4096
#define H_DIM  4096
#define V_DIM  128000
#define BM 256
#define BN 256
#define BK 64
#define NT_N (N_ROWS / BM)     // 16
#define NT_V (V_DIM / BN)      // 500
#define NK   (H_DIM / BK)      // 64
#define IGNORE_INDEX (-100)

typedef __attribute__((ext_vector_type(8))) short bf16x8;
typedef __attribute__((ext_vector_type(4))) float f32x4;
typedef const __attribute__((address_space(1))) unsigned int* gas1_u32;
typedef __attribute__((address_space(3))) unsigned int* las3_u32;

__device__ __forceinline__ unsigned short f2bf(float f) {
    union { float f; unsigned int u; } v; v.f = f;
    return (unsigned short)((v.u + 0x8000u) >> 16);  // round-half-up to bf16
}

// ---------------- fp32 -> bf16 conversion (memory-bound) ----------------
__global__ void cvt_f32_bf16_kernel(const float* __restrict__ in,
                                    ushort* __restrict__ out, size_t n)
{
    size_t i = ((size_t)blockIdx.x * blockDim.x + threadIdx.x) * 8;
    size_t stride = (size_t)gridDim.x * blockDim.x * 8;
    for (; i < n; i += stride) {
        f32x4 a = *(const f32x4*)(in + i);
        f32x4 b = *(const f32x4*)(in + i + 4);
        ushort4 o0 = { f2bf(a.x), f2bf(a.y), f2bf(a.z), f2bf(a.w) };
        ushort4 o1 = { f2bf(b.x), f2bf(b.y), f2bf(b.z), f2bf(b.w) };
        *(ushort4*)(out + i) = o0;
        *(ushort4*)(out + i + 4) = o1;
    }
}

#define BAR()    asm volatile("s_barrier" ::: "memory")
#define WAITV8() asm volatile("s_waitcnt vmcnt(8)" ::: "memory")
#define SETP1()  __builtin_amdgcn_s_setprio(1)
#define SETP0()  __builtin_amdgcn_s_setprio(0)

// stage one half-tile (2 x 16B gload_lds per thread); dest linear, src pre-swizzled
#define STAGE_A(BUF, HALF, KT)                                                        \
    { _Pragma("unroll")                                                               \
      for (int j_ = 0; j_ < 2; ++j_)                                                  \
          __builtin_amdgcn_global_load_lds(                                           \
              (gas1_u32)(gAr + (size_t)((HALF)*128 + j_*64) * 8192 + (size_t)(KT)*128),\
              (las3_u32)((char*)lsA + (BUF)*32768 + (HALF)*16384 + j_*8192 + tid*16), \
              16, 0, 0); }
#define STAGE_B(BUF, HALF, KT)                                                        \
    { _Pragma("unroll")                                                               \
      for (int j_ = 0; j_ < 2; ++j_)                                                  \
          __builtin_amdgcn_global_load_lds(                                           \
              (gas1_u32)(gBr + (size_t)((HALF)*128 + j_*64) * 8192 + (size_t)(KT)*128),\
              (las3_u32)((char*)lsB + (BUF)*32768 + (HALF)*16384 + j_*8192 + tid*16), \
              16, 0, 0); }

#define RD_ALO(BUF)                                                                   \
    { _Pragma("unroll")                                                               \
      for (int mi_ = 0; mi_ < 4; ++mi_) { _Pragma("unroll")                           \
        for (int ks_ = 0; ks_ < 2; ++ks_)                                             \
          aLo[mi_][ks_] = *(const bf16x8*)((const char*)lsA + (BUF)*32768 + offA[mi_][ks_]); } }
#define RD_AHI(BUF)                                                                   \
    { _Pragma("unroll")                                                               \
      for (int mi_ = 0; mi_ < 4; ++mi_) { _Pragma("unroll")                           \
        for (int ks_ = 0; ks_ < 2; ++ks_)                                             \
          aHi[mi_][ks_] = *(const bf16x8*)((const char*)lsA + (BUF)*32768 + offA[mi_ + 4][ks_]); } }
#define RD_BLO(BUF)                                                                   \
    { _Pragma("unroll")                                                               \
      for (int ni_ = 0; ni_ < 2; ++ni_) { _Pragma("unroll")                           \
        for (int ks_ = 0; ks_ < 2; ++ks_)                                             \
          bAll[ni_][ks_] = *(const bf16x8*)((const char*)lsB + (BUF)*32768 + offB[ni_][ks_]); } }
#define RD_BHI(BUF)                                                                   \
    { _Pragma("unroll")                                                               \
      for (int ni_ = 2; ni_ < 4; ++ni_) { _Pragma("unroll")                           \
        for (int ks_ = 0; ks_ < 2; ++ks_)                                             \
          bAll[ni_][ks_] = *(const bf16x8*)((const char*)lsB + (BUF)*32768 + offB[ni_][ks_]); } }

// ks outermost: consecutive MFMAs independent
#define MFMA_QUAD(AF, MIB, NIL)                                                       \
    { _Pragma("unroll")                                                               \
      for (int ks_ = 0; ks_ < 2; ++ks_) { _Pragma("unroll")                           \
        for (int mi_ = 0; mi_ < 4; ++mi_) { _Pragma("unroll")                         \
          for (int nn_ = 0; nn_ < 2; ++nn_)                                           \
            acc[(MIB)+mi_][(NIL)+nn_] = __builtin_amdgcn_mfma_f32_16x16x32_bf16(      \
                AF[mi_][ks_], bAll[(NIL)+nn_][ks_], acc[(MIB)+mi_][(NIL)+nn_], 0, 0, 0); } } }

// ------------------- 256^2 2-barrier-per-K-tile bf16 GEMM -------------------
__global__ __launch_bounds__(512, 1)
void lmce_gemm256_kernel(const ushort* __restrict__ Xb, const ushort* __restrict__ Wb,
                         float* __restrict__ pm, float* __restrict__ pl)
{
    // [buf][half][128 rows][64 k] bf16 = 16KB per half; 64KB per operand
    __shared__ __align__(16) ushort lsA[2][2][128 * 64];
    __shared__ __align__(16) ushort lsB[2][2][128 * 64];
    __shared__ float red_m[4][BM];
    __shared__ float red_l[4][BM];

    // bijective XCD swizzle: nwg = 8000, divisible by 8
    const int nwg = NT_N * NT_V;
    int orig = blockIdx.x;
    int wg = (orig & 7) * (nwg >> 3) + (orig >> 3);
    int vtile = wg / NT_N;
    int ntile = wg - vtile * NT_N;

    int tid  = threadIdx.x;
    int lane = tid & 63;
    int w    = tid >> 6;         // 0..7
    int wr = w >> 2;             // 0..1 : which A half this wave consumes
    int wc = w & 3;              // 0..3 : which 64-row B strip
    int fr = lane & 15;
    int kg = lane >> 4;

    // staging source: thread covers row (tid>>3) of each 64-row chunk,
    // 16B at pre-swizzled col ((tid&7) ^ ((tid>>3)&7))*16
    int scolb = ((tid & 7) ^ ((tid >> 3) & 7)) * 16;
    const char* gAr = (const char*)Xb + (size_t)(ntile * BM + (tid >> 3)) * 8192 + scolb;
    const char* gBr = (const char*)Wb + (size_t)(vtile * BN + (tid >> 3)) * 8192 + scolb;

    // swizzled ds_read offsets (within one operand buffer; add buf*32768)
    int offA[8][2];
    #pragma unroll
    for (int mi = 0; mi < 8; ++mi)
        #pragma unroll
        for (int ks = 0; ks < 2; ++ks) {
            int row = mi * 16 + fr;     // local row in half wr
            offA[mi][ks] = wr * 16384 + row * 128 + ((kg * 16 + ks * 64) ^ ((row & 7) << 4));
        }
    int offB[4][2];
    #pragma unroll
    for (int ni = 0; ni < 4; ++ni)
        #pragma unroll
        for (int ks = 0; ks < 2; ++ks) {
            int rowh = (wc & 1) * 64 + ni * 16 + fr;   // local row in half wc>>1
            offB[ni][ks] = (wc >> 1) * 16384 + rowh * 128 + ((kg * 16 + ks * 64) ^ ((rowh & 7) << 4));
        }

    f32x4 acc[8][4];
    #pragma unroll
    for (int i = 0; i < 8; ++i)
        #pragma unroll
        for (int j = 0; j < 4; ++j)
            acc[i][j] = (f32x4){0.f, 0.f, 0.f, 0.f};

    bf16x8 aLo[4][2], aHi[4][2], bAll[4][2];

    // prologue: tile0 -> buf0 (8 loads), tile1 -> buf1 (8 loads)
    STAGE_A(0, 0, 0); STAGE_A(0, 1, 0); STAGE_B(0, 0, 0); STAGE_B(0, 1, 0);
    STAGE_A(1, 0, 1); STAGE_A(1, 1, 1); STAGE_B(1, 0, 1); STAGE_B(1, 1, 1);
    WAITV8();   // tile0's 8 loads landed (tile1's 8 may be in flight)
    BAR();

    for (int t = 0; t < NK; ++t) {
        int buf = t & 1;
        int t2 = (t + 2 < NK) ? t + 2 : NK - 1;   // clamped dummy re-stage at tail

        // all 24 ds_reads for this K-tile (same buffer: no intra-tile hazard).
        // Compiler interleaves counted lgkmcnt with the MFMA stream below.
        RD_ALO(buf); RD_BLO(buf); RD_BHI(buf); RD_AHI(buf);

        SETP1();
        MFMA_QUAD(aLo, 0, 0);   // uses first 12 reads
        MFMA_QUAD(aLo, 0, 2);   // + bHi
        MFMA_QUAD(aHi, 4, 2);   // + aHi
        MFMA_QUAD(aHi, 4, 0);
        SETP0();

        // every wave arrives only after all its reads were consumed -> after
        // this barrier the whole block is done reading buf: safe to overwrite.
        BAR();

        STAGE_A(buf, 0, t2); STAGE_A(buf, 1, t2);
        STAGE_B(buf, 0, t2); STAGE_B(buf, 1, t2);

        // outstanding: tile t+1 (8, oldest) + tile t+2 (8, just issued).
        // vmcnt(8): tile t+1 landed; barrier publishes it to all waves.
        WAITV8();
        BAR();
    }

    __syncthreads();   // full drain (vmcnt 0 + lgkm 0) before epilogue

    // Epilogue: per-row max and sumexp over this block's 256 cols.
    // C/D layout (16x16x32): col = lane&15 (fr), row = kg*4 + reg.
    #pragma unroll
    for (int mi = 0; mi < 8; ++mi) {
        #pragma unroll
        for (int j = 0; j < 4; ++j) {
            float mx = fmaxf(fmaxf(acc[mi][0][j], acc[mi][1][j]),
                             fmaxf(acc[mi][2][j], acc[mi][3][j]));
            #pragma unroll
            for (int s = 1; s < 16; s <<= 1)
                mx = fmaxf(mx, __shfl_xor(mx, s, 64));
            float se = 0.f;
            #pragma unroll
            for (int ni = 0; ni < 4; ++ni)
                se += __expf(acc[mi][ni][j] - mx);
            #pragma unroll
            for (int s = 1; s < 16; s <<= 1)
                se += __shfl_xor(se, s, 64);
            if (fr == 0) {
                int rloc = wr * 128 + mi * 16 + kg * 4 + j;
                red_m[wc][rloc] = mx;
                red_l[wc][rloc] = se;
            }
        }
    }
    __syncthreads();
    if (tid < BM) {
        float mm = red_m[0][tid], ll = red_l[0][tid];
        #pragma unroll
        for (int p = 1; p < 4; ++p) {
            float m2 = red_m[p][tid], l2 = red_l[p][tid];
            float m3 = fmaxf(mm, m2);
            ll = ll * __expf(mm - m3) + l2 * __expf(m2 - m3);
            mm = m3;
        }
        size_t idx = (size_t)vtile * N_ROWS + (size_t)(ntile * BM + tid);
        pm[idx] = mm;
        pl[idx] = ll;
    }
}

// tgt[row] = dot(x[row], W[y[row]]) in fp32 (exact vs reference)
__global__ void lmce_tgt_kernel(const float* __restrict__ X, const float* __restrict__ W,
                                const int* __restrict__ y, float* __restrict__ tgt)
{
    int row = blockIdx.x;
    int tid = threadIdx.x;
    int yv = y[row];
    float s = 0.f;
    if (yv >= 0 && yv < V_DIM) {
        const float* xr = X + (size_t)row * H_DIM;
        const float* wrow = W + (size_t)yv * H_DIM;
        #pragma unroll
        for (int j = 0; j < 4; ++j) {
            int idx = (tid + j * 256) * 4;
            f32x4 a = *(const f32x4*)(xr + idx);
            f32x4 b = *(const f32x4*)(wrow + idx);
            s += a.x * b.x + a.y * b.y + a.z * b.z + a.w * b.w;
        }
    }
    #pragma unroll
    for (int sh = 1; sh < 64; sh <<= 1) s += __shfl_xor(s, sh, 64);
    __shared__ float sred[4];
    if ((tid & 63) == 0) sred[tid >> 6] = s;
    __syncthreads();
    if (tid == 0) tgt[row] = sred[0] + sred[1] + sred[2] + sred[3];
}

// merge NT_V per-vtile (m,l) partials per row -> lse[row]
__global__ void lmce_lse_kernel(const float* __restrict__ pm, const float* __restrict__ pl,
                                float* __restrict__ lse)
{
    int tid = threadIdx.x;
    int row = blockIdx.x * 64 + (tid & 63);
    int part = tid >> 6;               // 0..3, each scans NT_V/4 = 125 vtiles
    const int per = NT_V / 4;
    float m = -INFINITY, l = 0.f;
    for (int vt = part * per; vt < (part + 1) * per; ++vt) {
        size_t idx = (size_t)vt * N_ROWS + row;
        float m2 = pm[idx], l2 = pl[idx];
        float mm = fmaxf(m, m2);
        l = l * __expf(m - mm) + l2 * __expf(m2 - mm);
        m = mm;
    }
    __shared__ float sm[4][64], sl[4][64];
    sm[part][tid & 63] = m;
    sl[part][tid & 63] = l;
    __syncthreads();
    if (tid < 64) {
        float M = sm[0][tid], L = sl[0][tid];
        #pragma unroll
        for (int p = 1; p < 4; ++p) {
            float m2 = sm[p][tid], l2 = sl[p][tid];
            float mm = fmaxf(M, m2);
            L = L * __expf(M - mm) + l2 * __expf(m2 - mm);
            M = mm;
        }
        lse[blockIdx.x * 64 + tid] = M + logf(L);
    }
}

__global__ void lmce_final_kernel(const float* __restrict__ lse, const float* __restrict__ tgt,
                                  const int* __restrict__ y, float* __restrict__ out)
{
    int tid = threadIdx.x;
    float s = 0.f, c = 0.f;
    for (int i = tid; i < N_ROWS; i += 256) {
        if (y[i] != IGNORE_INDEX) {
            s += lse[i] - tgt[i];
            c += 1.f;
        }
    }
    #pragma unroll
    for (int sh = 1; sh < 64; sh <<= 1) {
        s += __shfl_xor(s, sh, 64);
        c += __shfl_xor(c, sh, 64);
    }
    __shared__ float ss[4], cc[4];
    if ((tid & 63) == 0) { ss[tid >> 6] = s; cc[tid >> 6] = c; }
    __syncthreads();
    if (tid == 0) {
        float S = ss[0] + ss[1] + ss[2] + ss[3];
        float C = cc[0] + cc[1] + cc[2] + cc[3];
        out[0] = S / fmaxf(C, 1.f);
    }
}

extern "C" void kernel_launch(void* const* d_in, const int* in_sizes, int n_in,
                              void* d_out, int out_size, void* d_ws, size_t ws_size,
                              hipStream_t stream)
{
    const float* X = (const float*)d_in[0];   // [4096, 4096] fp32
    const int*   y = (const int*)d_in[1];     // [4096] labels
    const float* W = (const float*)d_in[2];   // [128000, 4096] fp32
    float* out = (float*)d_out;

    char* ws = (char*)d_ws;
    const size_t OFF_PL  = 16384000;
    const size_t OFF_TGT = 32768000;
    const size_t OFF_LSE = 32784384;
    const size_t OFF_XB  = 32800768;
    const size_t OFF_WB  = 66355200;

    float* pm  = (float*)ws;
    float* pl  = (float*)(ws + OFF_PL);
    float* tgt = (float*)(ws + OFF_TGT);
    float* lse = (float*)(ws + OFF_LSE);
    ushort* Xb = (ushort*)(ws + OFF_XB);
    ushort* Wb = (ushort*)(ws + OFF_WB);

    cvt_f32_bf16_kernel<<<2048, 256, 0, stream>>>(W, Wb, (size_t)V_DIM * H_DIM);
    cvt_f32_bf16_kernel<<<512, 256, 0, stream>>>(X, Xb, (size_t)N_ROWS * H_DIM);
    lmce_gemm256_kernel<<<NT_N * NT_V, 512, 0, stream>>>(Xb, Wb, pm, pl);
    lmce_tgt_kernel<<<N_ROWS, 256, 0, stream>>>(X, W, y, tgt);
    lmce_lse_kernel<<<N_ROWS / 64, 256, 0, stream>>>(pm, pl, lse);
    lmce_final_kernel<<<1, 256, 0, stream>>>(lse, tgt, y, out);
}

// Round 8
// 5133.961 us; speedup vs baseline: 1.0429x; 1.0429x over previous
//
#include <hip/hip_runtime.h>
#include <hip/hip_bf16.h>
#include <math.h>

// Fused LM-head cross-entropy: loss = mean_valid( logsumexp(x@W^T) - logit[y] )
// N=4096 tokens, H=4096 hidden, V=128000 vocab.
//
// Round 8: R6's 8-phase schedule (best so far) + one-phase-lookahead ds_read
// pipelining with counted lgkmcnt. Tile-head bundle (aLo,bLo,bHi) issues after
// the previous publish barrier; aHi issues in ph0. Waits: lgkm(12)/lgkm(8)/
// lgkm(0)/none across the 4 phases of a K-tile. vmcnt(6) ledger unchanged.

#define N_ROWS 4096
#define H_DIM  4096
#define V_DIM  128000
#define BM 256
#define BN 256
#define BK 64
#define NT_N (N_ROWS / BM)     // 16
#define NT_V (V_DIM / BN)      // 500
#define NK   (H_DIM / BK)      // 64
#define IGNORE_INDEX (-100)

typedef __attribute__((ext_vector_type(8))) short bf16x8;
typedef __attribute__((ext_vector_type(4))) float f32x4;
typedef const __attribute__((address_space(1))) unsigned int* gas1_u32;
typedef __attribute__((address_space(3))) unsigned int* las3_u32;

__device__ __forceinline__ unsigned short f2bf(float f) {
    union { float f; unsigned int u; } v; v.f = f;
    return (unsigned short)((v.u + 0x8000u) >> 16);  // round-half-up to bf16
}

// ---------------- fp32 -> bf16 conversion (memory-bound) ----------------
__global__ void cvt_f32_bf16_kernel(const float* __restrict__ in,
                                    ushort* __restrict__ out, size_t n)
{
    size_t i = ((size_t)blockIdx.x * blockDim.x + threadIdx.x) * 8;
    size_t stride = (size_t)gridDim.x * blockDim.x * 8;
    for (; i < n; i += stride) {
        f32x4 a = *(const f32x4*)(in + i);
        f32x4 b = *(const f32x4*)(in + i + 4);
        ushort4 o0 = { f2bf(a.x), f2bf(a.y), f2bf(a.z), f2bf(a.w) };
        ushort4 o1 = { f2bf(b.x), f2bf(b.y), f2bf(b.z), f2bf(b.w) };
        *(ushort4*)(out + i) = o0;
        *(ushort4*)(out + i + 4) = o1;
    }
}

#define BAR()    asm volatile("s_barrier" ::: "memory")
#define LGKM0()  asm volatile("s_waitcnt lgkmcnt(0)" ::: "memory")
#define LGKM8()  asm volatile("s_waitcnt lgkmcnt(8)" ::: "memory")
#define LGKM12() asm volatile("s_waitcnt lgkmcnt(12)" ::: "memory")
#define WAITV6() asm volatile("s_waitcnt vmcnt(6)" ::: "memory")
#define SETP1()  __builtin_amdgcn_s_setprio(1)
#define SETP0()  __builtin_amdgcn_s_setprio(0)

// stage one half-tile (2 x 16B gload_lds per thread); dest linear, src pre-swizzled
#define STAGE_A(BUF, HALF, KT)                                                        \
    { _Pragma("unroll")                                                               \
      for (int j_ = 0; j_ < 2; ++j_)                                                  \
          __builtin_amdgcn_global_load_lds(                                           \
              (gas1_u32)(gAr + (size_t)((HALF)*128 + j_*64) * 8192 + (size_t)(KT)*128),\
              (las3_u32)((char*)lsA + (BUF)*32768 + (HALF)*16384 + j_*8192 + tid*16), \
              16, 0, 0); }
#define STAGE_B(BUF, HALF, KT)                                                        \
    { _Pragma("unroll")                                                               \
      for (int j_ = 0; j_ < 2; ++j_)                                                  \
          __builtin_amdgcn_global_load_lds(                                           \
              (gas1_u32)(gBr + (size_t)((HALF)*128 + j_*64) * 8192 + (size_t)(KT)*128),\
              (las3_u32)((char*)lsB + (BUF)*32768 + (HALF)*16384 + j_*8192 + tid*16), \
              16, 0, 0); }

// issue order inside the bundle matters for the counted lgkm waits:
// aLo(8) then bLo(4) then bHi(4).
#define RD_ALO(BUF)                                                                   \
    { _Pragma("unroll")                                                               \
      for (int mi_ = 0; mi_ < 4; ++mi_) { _Pragma("unroll")                           \
        for (int ks_ = 0; ks_ < 2; ++ks_)                                             \
          aLo[mi_][ks_] = *(const bf16x8*)((const char*)lsA + (BUF)*32768 + offA[mi_][ks_]); } }
#define RD_AHI(BUF)                                                                   \
    { _Pragma("unroll")                                                               \
      for (int mi_ = 0; mi_ < 4; ++mi_) { _Pragma("unroll")                           \
        for (int ks_ = 0; ks_ < 2; ++ks_)                                             \
          aHi[mi_][ks_] = *(const bf16x8*)((const char*)lsA + (BUF)*32768 + offA[mi_ + 4][ks_]); } }
#define RD_BLO(BUF)                                                                   \
    { _Pragma("unroll")                                                               \
      for (int ni_ = 0; ni_ < 2; ++ni_) { _Pragma("unroll")                           \
        for (int ks_ = 0; ks_ < 2; ++ks_)                                             \
          bAll[ni_][ks_] = *(const bf16x8*)((const char*)lsB + (BUF)*32768 + offB[ni_][ks_]); } }
#define RD_BHI(BUF)                                                                   \
    { _Pragma("unroll")                                                               \
      for (int ni_ = 2; ni_ < 4; ++ni_) { _Pragma("unroll")                           \
        for (int ks_ = 0; ks_ < 2; ++ks_)                                             \
          bAll[ni_][ks_] = *(const bf16x8*)((const char*)lsB + (BUF)*32768 + offB[ni_][ks_]); } }

// ks outermost: consecutive MFMAs independent
#define MFMA_QUAD(AF, MIB, NIL)                                                       \
    { _Pragma("unroll")                                                               \
      for (int ks_ = 0; ks_ < 2; ++ks_) { _Pragma("unroll")                           \
        for (int mi_ = 0; mi_ < 4; ++mi_) { _Pragma("unroll")                         \
          for (int nn_ = 0; nn_ < 2; ++nn_)                                           \
            acc[(MIB)+mi_][(NIL)+nn_] = __builtin_amdgcn_mfma_f32_16x16x32_bf16(      \
                AF[mi_][ks_], bAll[(NIL)+nn_][ks_], acc[(MIB)+mi_][(NIL)+nn_], 0, 0, 0); } } }

// ------------------- 256^2 8-phase pipelined bf16 GEMM -------------------
__global__ __launch_bounds__(512, 1)
void lmce_gemm256_kernel(const ushort* __restrict__ Xb, const ushort* __restrict__ Wb,
                         float* __restrict__ pm, float* __restrict__ pl)
{
    // [buf][half][128 rows][64 k] bf16 = 16KB per half; 64KB per operand
    __shared__ __align__(16) ushort lsA[2][2][128 * 64];
    __shared__ __align__(16) ushort lsB[2][2][128 * 64];
    __shared__ float red_m[4][BM];
    __shared__ float red_l[4][BM];

    // bijective XCD swizzle: nwg = 8000, divisible by 8
    const int nwg = NT_N * NT_V;
    int orig = blockIdx.x;
    int wg = (orig & 7) * (nwg >> 3) + (orig >> 3);
    int vtile = wg / NT_N;
    int ntile = wg - vtile * NT_N;

    int tid  = threadIdx.x;
    int lane = tid & 63;
    int w    = tid >> 6;         // 0..7
    int wr = w >> 2;             // 0..1 : which A half this wave consumes
    int wc = w & 3;              // 0..3 : which 64-row B strip
    int fr = lane & 15;
    int kg = lane >> 4;

    // staging source: thread covers row (tid>>3) of each 64-row chunk,
    // 16B at pre-swizzled col ((tid&7) ^ ((tid>>3)&7))*16
    int scolb = ((tid & 7) ^ ((tid >> 3) & 7)) * 16;
    const char* gAr = (const char*)Xb + (size_t)(ntile * BM + (tid >> 3)) * 8192 + scolb;
    const char* gBr = (const char*)Wb + (size_t)(vtile * BN + (tid >> 3)) * 8192 + scolb;

    // swizzled ds_read offsets (within one operand buffer; add buf*32768)
    int offA[8][2];
    #pragma unroll
    for (int mi = 0; mi < 8; ++mi)
        #pragma unroll
        for (int ks = 0; ks < 2; ++ks) {
            int row = mi * 16 + fr;     // local row in half wr
            offA[mi][ks] = wr * 16384 + row * 128 + ((kg * 16 + ks * 64) ^ ((row & 7) << 4));
        }
    int offB[4][2];
    #pragma unroll
    for (int ni = 0; ni < 4; ++ni)
        #pragma unroll
        for (int ks = 0; ks < 2; ++ks) {
            int rowh = (wc & 1) * 64 + ni * 16 + fr;   // local row in half wc>>1
            offB[ni][ks] = (wc >> 1) * 16384 + rowh * 128 + ((kg * 16 + ks * 64) ^ ((rowh & 7) << 4));
        }

    f32x4 acc[8][4];
    #pragma unroll
    for (int i = 0; i < 8; ++i)
        #pragma unroll
        for (int j = 0; j < 4; ++j)
            acc[i][j] = (f32x4){0.f, 0.f, 0.f, 0.f};

    bf16x8 aLo[4][2], aHi[4][2], bAll[4][2];

    // prologue: tile0 (8 loads) + {B0(1),B1(1),A0(1)} (6 loads in flight)
    STAGE_A(0, 0, 0); STAGE_A(0, 1, 0); STAGE_B(0, 0, 0); STAGE_B(0, 1, 0);
    STAGE_B(1, 0, 1); STAGE_B(1, 1, 1); STAGE_A(1, 0, 1);
    WAITV6();
    BAR();
    // tile-0 head bundle: aLo(8), bLo(4), bHi(4)
    RD_ALO(0); RD_BLO(0); RD_BHI(0);

    for (int t = 0; t < NK; t += 2) {
        int t2 = (t + 2 < NK) ? t + 2 : NK - 1;   // clamped dummy re-stage at tail
        int t3 = (t + 3 < NK) ? t + 3 : NK - 1;

        // ---- ph0 (tile t, buf0): Q(mi0-3, ni0-1)
        RD_AHI(0);                 // for ph2 (one phase ahead)
        STAGE_A(1, 1, t + 1);
        BAR(); LGKM12();           // aLo+bLo retired; bHi(4)+aHi(8) may remain
        SETP1(); MFMA_QUAD(aLo, 0, 0); SETP0();
        BAR();

        // ---- ph1: Q(mi0-3, ni2-3)
        STAGE_B(0, 0, t2);
        BAR(); LGKM8();            // bHi retired; aHi(8) may remain
        SETP1(); MFMA_QUAD(aLo, 0, 2); SETP0();
        BAR();

        // ---- ph2: Q(mi4-7, ni2-3)
        STAGE_B(0, 1, t2);
        BAR(); LGKM0();            // aHi retired (issued a full phase earlier)
        SETP1(); MFMA_QUAD(aHi, 4, 2); SETP0();
        BAR();

        // ---- ph3: Q(mi4-7, ni0-1); all regs ready
        STAGE_A(0, 0, t2);
        BAR();
        SETP1(); MFMA_QUAD(aHi, 4, 0); SETP0();
        WAITV6();                  // tile t+1 (buf1) landed
        BAR();
        RD_ALO(1); RD_BLO(1); RD_BHI(1);   // tile t+1 head bundle

        // ---- ph4 (tile t+1, buf1): Q(mi0-3, ni0-1)
        RD_AHI(1);
        STAGE_A(0, 1, t2);
        BAR(); LGKM12();
        SETP1(); MFMA_QUAD(aLo, 0, 0); SETP0();
        BAR();

        // ---- ph5: Q(mi0-3, ni2-3)
        STAGE_B(1, 0, t3);
        BAR(); LGKM8();
        SETP1(); MFMA_QUAD(aLo, 0, 2); SETP0();
        BAR();

        // ---- ph6: Q(mi4-7, ni2-3)
        STAGE_B(1, 1, t3);
        BAR(); LGKM0();
        SETP1(); MFMA_QUAD(aHi, 4, 2); SETP0();
        BAR();

        // ---- ph7: Q(mi4-7, ni0-1)
        STAGE_A(1, 0, t3);
        BAR();
        SETP1(); MFMA_QUAD(aHi, 4, 0); SETP0();
        WAITV6();                  // tile t+2 (buf0) landed
        BAR();
        if (t + 2 < NK) { RD_ALO(0); RD_BLO(0); RD_BHI(0); }  // next tile head
    }

    __syncthreads();   // full drain (vmcnt 0 + lgkm 0) before epilogue

    // Epilogue: per-row max and sumexp over this block's 256 cols.
    // C/D layout (16x16x32): col = lane&15 (fr), row = kg*4 + reg.
    #pragma unroll
    for (int mi = 0; mi < 8; ++mi) {
        #pragma unroll
        for (int j = 0; j < 4; ++j) {
            float mx = fmaxf(fmaxf(acc[mi][0][j], acc[mi][1][j]),
                             fmaxf(acc[mi][2][j], acc[mi][3][j]));
            #pragma unroll
            for (int s = 1; s < 16; s <<= 1)
                mx = fmaxf(mx, __shfl_xor(mx, s, 64));
            float se = 0.f;
            #pragma unroll
            for (int ni = 0; ni < 4; ++ni)
                se += __expf(acc[mi][ni][j] - mx);
            #pragma unroll
            for (int s = 1; s < 16; s <<= 1)
                se += __shfl_xor(se, s, 64);
            if (fr == 0) {
                int rloc = wr * 128 + mi * 16 + kg * 4 + j;
                red_m[wc][rloc] = mx;
                red_l[wc][rloc] = se;
            }
        }
    }
    __syncthreads();
    if (tid < BM) {
        float mm = red_m[0][tid], ll = red_l[0][tid];
        #pragma unroll
        for (int p = 1; p < 4; ++p) {
            float m2 = red_m[p][tid], l2 = red_l[p][tid];
            float m3 = fmaxf(mm, m2);
            ll = ll * __expf(mm - m3) + l2 * __expf(m2 - m3);
            mm = m3;
        }
        size_t idx = (size_t)vtile * N_ROWS + (size_t)(ntile * BM + tid);
        pm[idx] = mm;
        pl[idx] = ll;
    }
}

// tgt[row] = dot(x[row], W[y[row]]) in fp32 (exact vs reference)
__global__ void lmce_tgt_kernel(const float* __restrict__ X, const float* __restrict__ W,
                                const int* __restrict__ y, float* __restrict__ tgt)
{
    int row = blockIdx.x;
    int tid = threadIdx.x;
    int yv = y[row];
    float s = 0.f;
    if (yv >= 0 && yv < V_DIM) {
        const float* xr = X + (size_t)row * H_DIM;
        const float* wrow = W + (size_t)yv * H_DIM;
        #pragma unroll
        for (int j = 0; j < 4; ++j) {
            int idx = (tid + j * 256) * 4;
            f32x4 a = *(const f32x4*)(xr + idx);
            f32x4 b = *(const f32x4*)(wrow + idx);
            s += a.x * b.x + a.y * b.y + a.z * b.z + a.w * b.w;
        }
    }
    #pragma unroll
    for (int sh = 1; sh < 64; sh <<= 1) s += __shfl_xor(s, sh, 64);
    __shared__ float sred[4];
    if ((tid & 63) == 0) sred[tid >> 6] = s;
    __syncthreads();
    if (tid == 0) tgt[row] = sred[0] + sred[1] + sred[2] + sred[3];
}

// merge NT_V per-vtile (m,l) partials per row -> lse[row]
__global__ void lmce_lse_kernel(const float* __restrict__ pm, const float* __restrict__ pl,
                                float* __restrict__ lse)
{
    int tid = threadIdx.x;
    int row = blockIdx.x * 64 + (tid & 63);
    int part = tid >> 6;               // 0..3, each scans NT_V/4 = 125 vtiles
    const int per = NT_V / 4;
    float m = -INFINITY, l = 0.f;
    for (int vt = part * per; vt < (part + 1) * per; ++vt) {
        size_t idx = (size_t)vt * N_ROWS + row;
        float m2 = pm[idx], l2 = pl[idx];
        float mm = fmaxf(m, m2);
        l = l * __expf(m - mm) + l2 * __expf(m2 - mm);
        m = mm;
    }
    __shared__ float sm[4][64], sl[4][64];
    sm[part][tid & 63] = m;
    sl[part][tid & 63] = l;
    __syncthreads();
    if (tid < 64) {
        float M = sm[0][tid], L = sl[0][tid];
        #pragma unroll
        for (int p = 1; p < 4; ++p) {
            float m2 = sm[p][tid], l2 = sl[p][tid];
            float mm = fmaxf(M, m2);
            L = L * __expf(M - mm) + l2 * __expf(m2 - mm);
            M = mm;
        }
        lse[blockIdx.x * 64 + tid] = M + logf(L);
    }
}

__global__ void lmce_final_kernel(const float* __restrict__ lse, const float* __restrict__ tgt,
                                  const int* __restrict__ y, float* __restrict__ out)
{
    int tid = threadIdx.x;
    float s = 0.f, c = 0.f;
    for (int i = tid; i < N_ROWS; i += 256) {
        if (y[i] != IGNORE_INDEX) {
            s += lse[i] - tgt[i];
            c += 1.f;
        }
    }
    #pragma unroll
    for (int sh = 1; sh < 64; sh <<= 1) {
        s += __shfl_xor(s, sh, 64);
        c += __shfl_xor(c, sh, 64);
    }
    __shared__ float ss[4], cc[4];
    if ((tid & 63) == 0) { ss[tid >> 6] = s; cc[tid >> 6] = c; }
    __syncthreads();
    if (tid == 0) {
        float S = ss[0] + ss[1] + ss[2] + ss[3];
        float C = cc[0] + cc[1] + cc[2] + cc[3];
        out[0] = S / fmaxf(C, 1.f);
    }
}

extern "C" void kernel_launch(void* const* d_in, const int* in_sizes, int n_in,
                              void* d_out, int out_size, void* d_ws, size_t ws_size,
                              hipStream_t stream)
{
    const float* X = (const float*)d_in[0];   // [4096, 4096] fp32
    const int*   y = (const int*)d_in[1];     // [4096] labels
    const float* W = (const float*)d_in[2];   // [128000, 4096] fp32
    float* out = (float*)d_out;

    char* ws = (char*)d_ws;
    const size_t OFF_PL  = 16384000;
    const size_t OFF_TGT = 32768000;
    const size_t OFF_LSE = 32784384;
    const size_t OFF_XB  = 32800768;
    const size_t OFF_WB  = 66355200;

    float* pm  = (float*)ws;
    float* pl  = (float*)(ws + OFF_PL);
    float* tgt = (float*)(ws + OFF_TGT);
    float* lse = (float*)(ws + OFF_LSE);
    ushort* Xb = (ushort*)(ws + OFF_XB);
    ushort* Wb = (ushort*)(ws + OFF_WB);

    cvt_f32_bf16_kernel<<<2048, 256, 0, stream>>>(W, Wb, (size_t)V_DIM * H_DIM);
    cvt_f32_bf16_kernel<<<512, 256, 0, stream>>>(X, Xb, (size_t)N_ROWS * H_DIM);
    lmce_gemm256_kernel<<<NT_N * NT_V, 512, 0, stream>>>(Xb, Wb, pm, pl);
    lmce_tgt_kernel<<<N_ROWS, 256, 0, stream>>>(X, W, y, tgt);
    lmce_lse_kernel<<<N_ROWS / 64, 256, 0, stream>>>(pm, pl, lse);
    lmce_final_kernel<<<1, 256, 0, stream>>>(lse, tgt, y, out);
}

// Round 9
// 4698.624 us; speedup vs baseline: 1.1395x; 1.0927x over previous
//
#include <hip/hip_runtime.h>
#include <hip/hip_bf16.h>
#include <math.h>

// Fused LM-head cross-entropy: loss = mean_valid( logsumexp(x@W^T) - logit[y] )
// N=4096 tokens, H=4096 hidden, V=128000 vocab.
//
// Round 9: R6's 8-phase schedule (best: 4.43ms GEMM) with ONE change: the
// explicit "s_waitcnt lgkmcnt(0)" before each MFMA cluster is REMOVED. The
// compiler emits fine-grained counted lgkmcnt at each MFMA's first use of a
// loaded fragment (verified compiler behavior, m97), so the per-phase
// ds_read drain overlaps the MFMA stream instead of serializing before it.
// Barriers / vmcnt(6) ledger / swizzle unchanged.

#define N_ROWS 4096
#define H_DIM  4096
#define V_DIM  128000
#define BM 256
#define BN 256
#define BK 64
#define NT_N (N_ROWS / BM)     // 16
#define NT_V (V_DIM / BN)      // 500
#define NK   (H_DIM / BK)      // 64
#define IGNORE_INDEX (-100)

typedef __attribute__((ext_vector_type(8))) short bf16x8;
typedef __attribute__((ext_vector_type(4))) float f32x4;
typedef const __attribute__((address_space(1))) unsigned int* gas1_u32;
typedef __attribute__((address_space(3))) unsigned int* las3_u32;

__device__ __forceinline__ unsigned short f2bf(float f) {
    union { float f; unsigned int u; } v; v.f = f;
    return (unsigned short)((v.u + 0x8000u) >> 16);  // round-half-up to bf16
}

// ---------------- fp32 -> bf16 conversion (memory-bound) ----------------
__global__ void cvt_f32_bf16_kernel(const float* __restrict__ in,
                                    ushort* __restrict__ out, size_t n)
{
    size_t i = ((size_t)blockIdx.x * blockDim.x + threadIdx.x) * 8;
    size_t stride = (size_t)gridDim.x * blockDim.x * 8;
    for (; i < n; i += stride) {
        f32x4 a = *(const f32x4*)(in + i);
        f32x4 b = *(const f32x4*)(in + i + 4);
        ushort4 o0 = { f2bf(a.x), f2bf(a.y), f2bf(a.z), f2bf(a.w) };
        ushort4 o1 = { f2bf(b.x), f2bf(b.y), f2bf(b.z), f2bf(b.w) };
        *(ushort4*)(out + i) = o0;
        *(ushort4*)(out + i + 4) = o1;
    }
}

#define BAR()    asm volatile("s_barrier" ::: "memory")
#define WAITV6() asm volatile("s_waitcnt vmcnt(6)" ::: "memory")
#define SETP1()  __builtin_amdgcn_s_setprio(1)
#define SETP0()  __builtin_amdgcn_s_setprio(0)

// stage one half-tile (2 x 16B gload_lds per thread); dest linear, src pre-swizzled
#define STAGE_A(BUF, HALF, KT)                                                        \
    { _Pragma("unroll")                                                               \
      for (int j_ = 0; j_ < 2; ++j_)                                                  \
          __builtin_amdgcn_global_load_lds(                                           \
              (gas1_u32)(gAr + (size_t)((HALF)*128 + j_*64) * 8192 + (size_t)(KT)*128),\
              (las3_u32)((char*)lsA + (BUF)*32768 + (HALF)*16384 + j_*8192 + tid*16), \
              16, 0, 0); }
#define STAGE_B(BUF, HALF, KT)                                                        \
    { _Pragma("unroll")                                                               \
      for (int j_ = 0; j_ < 2; ++j_)                                                  \
          __builtin_amdgcn_global_load_lds(                                           \
              (gas1_u32)(gBr + (size_t)((HALF)*128 + j_*64) * 8192 + (size_t)(KT)*128),\
              (las3_u32)((char*)lsB + (BUF)*32768 + (HALF)*16384 + j_*8192 + tid*16), \
              16, 0, 0); }

#define RD_ALO(BUF)                                                                   \
    { _Pragma("unroll")                                                               \
      for (int mi_ = 0; mi_ < 4; ++mi_) { _Pragma("unroll")                           \
        for (int ks_ = 0; ks_ < 2; ++ks_)                                             \
          aLo[mi_][ks_] = *(const bf16x8*)((const char*)lsA + (BUF)*32768 + offA[mi_][ks_]); } }
#define RD_AHI(BUF)                                                                   \
    { _Pragma("unroll")                                                               \
      for (int mi_ = 0; mi_ < 4; ++mi_) { _Pragma("unroll")                           \
        for (int ks_ = 0; ks_ < 2; ++ks_)                                             \
          aHi[mi_][ks_] = *(const bf16x8*)((const char*)lsA + (BUF)*32768 + offA[mi_ + 4][ks_]); } }
#define RD_BLO(BUF)                                                                   \
    { _Pragma("unroll")                                                               \
      for (int ni_ = 0; ni_ < 2; ++ni_) { _Pragma("unroll")                           \
        for (int ks_ = 0; ks_ < 2; ++ks_)                                             \
          bAll[ni_][ks_] = *(const bf16x8*)((const char*)lsB + (BUF)*32768 + offB[ni_][ks_]); } }
#define RD_BHI(BUF)                                                                   \
    { _Pragma("unroll")                                                               \
      for (int ni_ = 2; ni_ < 4; ++ni_) { _Pragma("unroll")                           \
        for (int ks_ = 0; ks_ < 2; ++ks_)                                             \
          bAll[ni_][ks_] = *(const bf16x8*)((const char*)lsB + (BUF)*32768 + offB[ni_][ks_]); } }

// ks outermost: consecutive MFMAs independent
#define MFMA_QUAD(AF, MIB, NIL)                                                       \
    { _Pragma("unroll")                                                               \
      for (int ks_ = 0; ks_ < 2; ++ks_) { _Pragma("unroll")                           \
        for (int mi_ = 0; mi_ < 4; ++mi_) { _Pragma("unroll")                         \
          for (int nn_ = 0; nn_ < 2; ++nn_)                                           \
            acc[(MIB)+mi_][(NIL)+nn_] = __builtin_amdgcn_mfma_f32_16x16x32_bf16(      \
                AF[mi_][ks_], bAll[(NIL)+nn_][ks_], acc[(MIB)+mi_][(NIL)+nn_], 0, 0, 0); } } }

// ------------------- 256^2 8-phase bf16 GEMM -------------------
__global__ __launch_bounds__(512, 2)
void lmce_gemm256_kernel(const ushort* __restrict__ Xb, const ushort* __restrict__ Wb,
                         float* __restrict__ pm, float* __restrict__ pl)
{
    // [buf][half][128 rows][64 k] bf16 = 16KB per half; 64KB per operand
    __shared__ __align__(16) ushort lsA[2][2][128 * 64];
    __shared__ __align__(16) ushort lsB[2][2][128 * 64];
    __shared__ float red_m[4][BM];
    __shared__ float red_l[4][BM];

    // bijective XCD swizzle: nwg = 8000, divisible by 8
    const int nwg = NT_N * NT_V;
    int orig = blockIdx.x;
    int wg = (orig & 7) * (nwg >> 3) + (orig >> 3);
    int vtile = wg / NT_N;
    int ntile = wg - vtile * NT_N;

    int tid  = threadIdx.x;
    int lane = tid & 63;
    int w    = tid >> 6;         // 0..7
    int wr = w >> 2;             // 0..1 : which A half this wave consumes
    int wc = w & 3;              // 0..3 : which 64-row B strip
    int fr = lane & 15;
    int kg = lane >> 4;

    // staging source: thread covers row (tid>>3) of each 64-row chunk,
    // 16B at pre-swizzled col ((tid&7) ^ ((tid>>3)&7))*16
    int scolb = ((tid & 7) ^ ((tid >> 3) & 7)) * 16;
    const char* gAr = (const char*)Xb + (size_t)(ntile * BM + (tid >> 3)) * 8192 + scolb;
    const char* gBr = (const char*)Wb + (size_t)(vtile * BN + (tid >> 3)) * 8192 + scolb;

    // swizzled ds_read offsets (within one operand buffer; add buf*32768)
    int offA[8][2];
    #pragma unroll
    for (int mi = 0; mi < 8; ++mi)
        #pragma unroll
        for (int ks = 0; ks < 2; ++ks) {
            int row = mi * 16 + fr;     // local row in half wr
            offA[mi][ks] = wr * 16384 + row * 128 + ((kg * 16 + ks * 64) ^ ((row & 7) << 4));
        }
    int offB[4][2];
    #pragma unroll
    for (int ni = 0; ni < 4; ++ni)
        #pragma unroll
        for (int ks = 0; ks < 2; ++ks) {
            int rowh = (wc & 1) * 64 + ni * 16 + fr;   // local row in half wc>>1
            offB[ni][ks] = (wc >> 1) * 16384 + rowh * 128 + ((kg * 16 + ks * 64) ^ ((rowh & 7) << 4));
        }

    f32x4 acc[8][4];
    #pragma unroll
    for (int i = 0; i < 8; ++i)
        #pragma unroll
        for (int j = 0; j < 4; ++j)
            acc[i][j] = (f32x4){0.f, 0.f, 0.f, 0.f};

    bf16x8 aLo[4][2], aHi[4][2], bAll[4][2];

    // prologue: tile0 (8 loads) + {B0(1),B1(1),A0(1)} (6 loads in flight)
    STAGE_A(0, 0, 0); STAGE_A(0, 1, 0); STAGE_B(0, 0, 0); STAGE_B(0, 1, 0);
    STAGE_B(1, 0, 1); STAGE_B(1, 1, 1); STAGE_A(1, 0, 1);
    WAITV6();
    BAR();

    for (int t = 0; t < NK; t += 2) {
        int t2 = (t + 2 < NK) ? t + 2 : NK - 1;   // clamped dummy re-stage at tail
        int t3 = (t + 3 < NK) ? t + 3 : NK - 1;

        // ---- ph0 (tile t, buf0): Q(mi0-3, ni0-1)
        RD_ALO(0); RD_BLO(0);
        STAGE_A(1, 1, t + 1);
        BAR();                     // compiler emits counted lgkm waits at uses
        SETP1(); MFMA_QUAD(aLo, 0, 0); SETP0();
        BAR();

        // ---- ph1: Q(mi0-3, ni2-3)
        RD_BHI(0);
        STAGE_B(0, 0, t2);
        BAR();
        SETP1(); MFMA_QUAD(aLo, 0, 2); SETP0();
        BAR();

        // ---- ph2: Q(mi4-7, ni2-3)
        RD_AHI(0);
        STAGE_B(0, 1, t2);
        BAR();
        SETP1(); MFMA_QUAD(aHi, 4, 2); SETP0();
        BAR();

        // ---- ph3: Q(mi4-7, ni0-1); tile t+1 must land before ph4 reads
        STAGE_A(0, 0, t2);
        BAR();
        SETP1(); MFMA_QUAD(aHi, 4, 0); SETP0();
        WAITV6();
        BAR();

        // ---- ph4 (tile t+1, buf1): Q(mi0-3, ni0-1)
        RD_ALO(1); RD_BLO(1);
        STAGE_A(0, 1, t2);
        BAR();
        SETP1(); MFMA_QUAD(aLo, 0, 0); SETP0();
        BAR();

        // ---- ph5: Q(mi0-3, ni2-3)
        RD_BHI(1);
        STAGE_B(1, 0, t3);
        BAR();
        SETP1(); MFMA_QUAD(aLo, 0, 2); SETP0();
        BAR();

        // ---- ph6: Q(mi4-7, ni2-3)
        RD_AHI(1);
        STAGE_B(1, 1, t3);
        BAR();
        SETP1(); MFMA_QUAD(aHi, 4, 2); SETP0();
        BAR();

        // ---- ph7: Q(mi4-7, ni0-1); tile t+2 must land before next ph0 reads
        STAGE_A(1, 0, t3);
        BAR();
        SETP1(); MFMA_QUAD(aHi, 4, 0); SETP0();
        WAITV6();
        BAR();
    }

    __syncthreads();   // full drain (vmcnt 0 + lgkm 0) before epilogue

    // Epilogue: per-row max and sumexp over this block's 256 cols.
    // C/D layout (16x16x32): col = lane&15 (fr), row = kg*4 + reg.
    #pragma unroll
    for (int mi = 0; mi < 8; ++mi) {
        #pragma unroll
        for (int j = 0; j < 4; ++j) {
            float mx = fmaxf(fmaxf(acc[mi][0][j], acc[mi][1][j]),
                             fmaxf(acc[mi][2][j], acc[mi][3][j]));
            #pragma unroll
            for (int s = 1; s < 16; s <<= 1)
                mx = fmaxf(mx, __shfl_xor(mx, s, 64));
            float se = 0.f;
            #pragma unroll
            for (int ni = 0; ni < 4; ++ni)
                se += __expf(acc[mi][ni][j] - mx);
            #pragma unroll
            for (int s = 1; s < 16; s <<= 1)
                se += __shfl_xor(se, s, 64);
            if (fr == 0) {
                int rloc = wr * 128 + mi * 16 + kg * 4 + j;
                red_m[wc][rloc] = mx;
                red_l[wc][rloc] = se;
            }
        }
    }
    __syncthreads();
    if (tid < BM) {
        float mm = red_m[0][tid], ll = red_l[0][tid];
        #pragma unroll
        for (int p = 1; p < 4; ++p) {
            float m2 = red_m[p][tid], l2 = red_l[p][tid];
            float m3 = fmaxf(mm, m2);
            ll = ll * __expf(mm - m3) + l2 * __expf(m2 - m3);
            mm = m3;
        }
        size_t idx = (size_t)vtile * N_ROWS + (size_t)(ntile * BM + tid);
        pm[idx] = mm;
        pl[idx] = ll;
    }
}

// tgt[row] = dot(x[row], W[y[row]]) in fp32 (exact vs reference)
__global__ void lmce_tgt_kernel(const float* __restrict__ X, const float* __restrict__ W,
                                const int* __restrict__ y, float* __restrict__ tgt)
{
    int row = blockIdx.x;
    int tid = threadIdx.x;
    int yv = y[row];
    float s = 0.f;
    if (yv >= 0 && yv < V_DIM) {
        const float* xr = X + (size_t)row * H_DIM;
        const float* wrow = W + (size_t)yv * H_DIM;
        #pragma unroll
        for (int j = 0; j < 4; ++j) {
            int idx = (tid + j * 256) * 4;
            f32x4 a = *(const f32x4*)(xr + idx);
            f32x4 b = *(const f32x4*)(wrow + idx);
            s += a.x * b.x + a.y * b.y + a.z * b.z + a.w * b.w;
        }
    }
    #pragma unroll
    for (int sh = 1; sh < 64; sh <<= 1) s += __shfl_xor(s, sh, 64);
    __shared__ float sred[4];
    if ((tid & 63) == 0) sred[tid >> 6] = s;
    __syncthreads();
    if (tid == 0) tgt[row] = sred[0] + sred[1] + sred[2] + sred[3];
}

// merge NT_V per-vtile (m,l) partials per row -> lse[row]
__global__ void lmce_lse_kernel(const float* __restrict__ pm, const float* __restrict__ pl,
                                float* __restrict__ lse)
{
    int tid = threadIdx.x;
    int row = blockIdx.x * 64 + (tid & 63);
    int part = tid >> 6;               // 0..3, each scans NT_V/4 = 125 vtiles
    const int per = NT_V / 4;
    float m = -INFINITY, l = 0.f;
    for (int vt = part * per; vt < (part + 1) * per; ++vt) {
        size_t idx = (size_t)vt * N_ROWS + row;
        float m2 = pm[idx], l2 = pl[idx];
        float mm = fmaxf(m, m2);
        l = l * __expf(m - mm) + l2 * __expf(m2 - mm);
        m = mm;
    }
    __shared__ float sm[4][64], sl[4][64];
    sm[part][tid & 63] = m;
    sl[part][tid & 63] = l;
    __syncthreads();
    if (tid < 64) {
        float M = sm[0][tid], L = sl[0][tid];
        #pragma unroll
        for (int p = 1; p < 4; ++p) {
            float m2 = sm[p][tid], l2 = sl[p][tid];
            float mm = fmaxf(M, m2);
            L = L * __expf(M - mm) + l2 * __expf(m2 - mm);
            M = mm;
        }
        lse[blockIdx.x * 64 + tid] = M + logf(L);
    }
}

__global__ void lmce_final_kernel(const float* __restrict__ lse, const float* __restrict__ tgt,
                                  const int* __restrict__ y, float* __restrict__ out)
{
    int tid = threadIdx.x;
    float s = 0.f, c = 0.f;
    for (int i = tid; i < N_ROWS; i += 256) {
        if (y[i] != IGNORE_INDEX) {
            s += lse[i] - tgt[i];
            c += 1.f;
        }
    }
    #pragma unroll
    for (int sh = 1; sh < 64; sh <<= 1) {
        s += __shfl_xor(s, sh, 64);
        c += __shfl_xor(c, sh, 64);
    }
    __shared__ float ss[4], cc[4];
    if ((tid & 63) == 0) { ss[tid >> 6] = s; cc[tid >> 6] = c; }
    __syncthreads();
    if (tid == 0) {
        float S = ss[0] + ss[1] + ss[2] + ss[3];
        float C = cc[0] + cc[1] + cc[2] + cc[3];
        out[0] = S / fmaxf(C, 1.f);
    }
}

extern "C" void kernel_launch(void* const* d_in, const int* in_sizes, int n_in,
                              void* d_out, int out_size, void* d_ws, size_t ws_size,
                              hipStream_t stream)
{
    const float* X = (const float*)d_in[0];   // [4096, 4096] fp32
    const int*   y = (const int*)d_in[1];     // [4096] labels
    const float* W = (const float*)d_in[2];   // [128000, 4096] fp32
    float* out = (float*)d_out;

    char* ws = (char*)d_ws;
    const size_t OFF_PL  = 16384000;
    const size_t OFF_TGT = 32768000;
    const size_t OFF_LSE = 32784384;
    const size_t OFF_XB  = 32800768;
    const size_t OFF_WB  = 66355200;

    float* pm  = (float*)ws;
    float* pl  = (float*)(ws + OFF_PL);
    float* tgt = (float*)(ws + OFF_TGT);
    float* lse = (float*)(ws + OFF_LSE);
    ushort* Xb = (ushort*)(ws + OFF_XB);
    ushort* Wb = (ushort*)(ws + OFF_WB);

    cvt_f32_bf16_kernel<<<2048, 256, 0, stream>>>(W, Wb, (size_t)V_DIM * H_DIM);
    cvt_f32_bf16_kernel<<<512, 256, 0, stream>>>(X, Xb, (size_t)N_ROWS * H_DIM);
    lmce_gemm256_kernel<<<NT_N * NT_V, 512, 0, stream>>>(Xb, Wb, pm, pl);
    lmce_tgt_kernel<<<N_ROWS, 256, 0, stream>>>(X, W, y, tgt);
    lmce_lse_kernel<<<N_ROWS / 64, 256, 0, stream>>>(pm, pl, lse);
    lmce_final_kernel<<<1, 256, 0, stream>>>(lse, tgt, y, out);
}

// Round 10
// 3321.021 us; speedup vs baseline: 1.6122x; 1.4148x over previous
//
#include <hip/hip_runtime.h>
#include <hip/hip_bf16.h>
#include <math.h>

// Fused LM-head cross-entropy: loss = mean_valid( logsumexp(x@W^T) - logit[y] )
// N=4096 tokens, H=4096 hidden, V=128000 vocab.
//
// Round 10: MX-fp8 GEMM via mfma_scale_f32_32x32x64_f8f6f4 with IDENTITY
// scales (inert under any scale semantics). W pre-scaled x64 into e4m3
// (avoids subnormal floor), epilogue multiplies by 2^-6 exactly. BK=128
// (1B/elem) keeps the exact LDS byte geometry / staging / vmcnt(6) ledger /
// XOR swizzle of the validated R6 8-phase skeleton; NK=32 halves barriers.

#define N_ROWS 4096
#define H_DIM  4096
#define V_DIM  128000
#define BM 256
#define BN 256
#define BKB 128                 // K-bytes per tile (128 fp8 elems)
#define NT_N (N_ROWS / BM)      // 16
#define NT_V (V_DIM / BN)       // 500
#define NKT  (H_DIM / 128)      // 32 K-tiles
#define IGNORE_INDEX (-100)

typedef __attribute__((ext_vector_type(4))) int   i32x4;
typedef __attribute__((ext_vector_type(8))) int   i32x8;
typedef __attribute__((ext_vector_type(4))) float f32x4;
typedef __attribute__((ext_vector_type(16))) float f32x16;
typedef const __attribute__((address_space(1))) unsigned int* gas1_u32;
typedef __attribute__((address_space(3))) unsigned int* las3_u32;

// ---------------- exact f32 -> e4m3fn (OCP), RNE, saturating ----------------
__device__ __forceinline__ unsigned f2e4m3(float f) {
    unsigned u = __float_as_uint(f);
    unsigned s = (u >> 24) & 0x80u;
    float af = __uint_as_float(u & 0x7FFFFFFFu);
    unsigned code;
    if (af >= 0.015625f) {                       // normal range [2^-6, 448]
        if (af > 448.f) af = 448.f;
        unsigned v = __float_as_uint(af);
        v += 0x7FFFFu + ((v >> 20) & 1u);        // RNE to 3 mantissa bits
        unsigned m3 = (v >> 20) & 7u;
        int E = (int)(v >> 23) - 127;
        if (E > 8) { E = 8; m3 = 6u; }           // clamp to 448
        code = (unsigned)((E + 7) << 3) | m3;
    } else {                                      // subnormal: m * 2^-9
        code = (unsigned)rintf(af * 512.0f);     // 0..8 (8 -> 2^-6 seamlessly)
    }
    return s | code;
}

__global__ void cvt_f32_fp8_kernel(const float* __restrict__ in,
                                   unsigned char* __restrict__ out, size_t n, float scale)
{
    size_t i = ((size_t)blockIdx.x * blockDim.x + threadIdx.x) * 8;
    size_t stride = (size_t)gridDim.x * blockDim.x * 8;
    for (; i < n; i += stride) {
        f32x4 a = *(const f32x4*)(in + i);
        f32x4 b = *(const f32x4*)(in + i + 4);
        unsigned long long o;
        o  = (unsigned long long)f2e4m3(a.x * scale);
        o |= (unsigned long long)f2e4m3(a.y * scale) << 8;
        o |= (unsigned long long)f2e4m3(a.z * scale) << 16;
        o |= (unsigned long long)f2e4m3(a.w * scale) << 24;
        o |= (unsigned long long)f2e4m3(b.x * scale) << 32;
        o |= (unsigned long long)f2e4m3(b.y * scale) << 40;
        o |= (unsigned long long)f2e4m3(b.z * scale) << 48;
        o |= (unsigned long long)f2e4m3(b.w * scale) << 56;
        *(unsigned long long*)(out + i) = o;
    }
}

#define BAR()    asm volatile("s_barrier" ::: "memory")
#define WAITV6() asm volatile("s_waitcnt vmcnt(6)" ::: "memory")
#define SETP1()  __builtin_amdgcn_s_setprio(1)
#define SETP0()  __builtin_amdgcn_s_setprio(0)
#define SCL1 ((int)0x7F7F7F7F)   // E8M0 127 = 2^0 in every byte (identity)

// stage one half-tile (2 x 16B gload_lds per thread); dest linear, src pre-swizzled
#define STAGE_A(BUF, HALF, KT)                                                         \
    { _Pragma("unroll")                                                                \
      for (int j_ = 0; j_ < 2; ++j_)                                                   \
          __builtin_amdgcn_global_load_lds(                                            \
              (gas1_u32)(gAr + (size_t)((HALF)*128 + j_*64) * 4096 + (size_t)(KT)*128),\
              (las3_u32)((char*)lsA + (BUF)*32768 + (HALF)*16384 + j_*8192 + tid*16),  \
              16, 0, 0); }
#define STAGE_B(BUF, HALF, KT)                                                         \
    { _Pragma("unroll")                                                                \
      for (int j_ = 0; j_ < 2; ++j_)                                                   \
          __builtin_amdgcn_global_load_lds(                                            \
              (gas1_u32)(gBr + (size_t)((HALF)*128 + j_*64) * 4096 + (size_t)(KT)*128),\
              (las3_u32)((char*)lsB + (BUF)*32768 + (HALF)*16384 + j_*8192 + tid*16),  \
              16, 0, 0); }

// 32B fragment read: low 16B at off, high 16B at off^16 (kb is 32-aligned so
// (kb+16)^x == (kb^x)^16 -- keeps k-ascending byte order under the swizzle).
__device__ __forceinline__ i32x8 rd32(const char* base, int off) {
    i32x8 r;
    *(i32x4*)&r       = *(const i32x4*)(base + off);
    *((i32x4*)&r + 1) = *(const i32x4*)(base + (off ^ 16));
    return r;
}

#define RD_ALO(BUF) { _Pragma("unroll") for (int m_=0;m_<2;++m_) { _Pragma("unroll")   \
    for (int k_=0;k_<2;++k_) aLo[m_][k_] = rd32(lsAc + (BUF)*32768, offA[m_][k_]); } }
#define RD_AHI(BUF) { _Pragma("unroll") for (int m_=0;m_<2;++m_) { _Pragma("unroll")   \
    for (int k_=0;k_<2;++k_) aHi[m_][k_] = rd32(lsAc + (BUF)*32768, offA[m_+2][k_]); } }
#define RD_BLO(BUF) { _Pragma("unroll")                                                \
    for (int k_=0;k_<2;++k_) bF[0][k_] = rd32(lsBc + (BUF)*32768, offB[0][k_]); }
#define RD_BHI(BUF) { _Pragma("unroll")                                                \
    for (int k_=0;k_<2;++k_) bF[1][k_] = rd32(lsBc + (BUF)*32768, offB[1][k_]); }

// ks outermost: consecutive MFMAs independent
#define MFMA_PH(AF, MB, NI)                                                            \
    { _Pragma("unroll")                                                                \
      for (int ks_=0; ks_<2; ++ks_) { _Pragma("unroll")                                \
        for (int m_=0; m_<2; ++m_)                                                     \
          acc[(MB)+m_][NI] = __builtin_amdgcn_mfma_scale_f32_32x32x64_f8f6f4(          \
              AF[m_][ks_], bF[NI][ks_], acc[(MB)+m_][NI],                              \
              0, 0, 0, SCL1, 0, SCL1); } }

// ------------------- 256^2 8-phase MX-fp8 GEMM -------------------
__global__ __launch_bounds__(512, 2)
void lmce_gemm256_kernel(const unsigned char* __restrict__ Xq, const unsigned char* __restrict__ Wq,
                         float* __restrict__ pm, float* __restrict__ pl)
{
    // [buf][half][128 rows][128 k-bytes] = 16KB per half; 64KB per operand
    __shared__ __align__(16) char lsA[2][2][128 * 128];
    __shared__ __align__(16) char lsB[2][2][128 * 128];
    __shared__ float red_m[4][BM];
    __shared__ float red_l[4][BM];
    const char* lsAc = (const char*)lsA;
    const char* lsBc = (const char*)lsB;

    // bijective XCD swizzle: nwg = 8000, divisible by 8
    const int nwg = NT_N * NT_V;
    int orig = blockIdx.x;
    int wg = (orig & 7) * (nwg >> 3) + (orig >> 3);
    int vtile = wg / NT_N;
    int ntile = wg - vtile * NT_N;

    int tid  = threadIdx.x;
    int lane = tid & 63;
    int w    = tid >> 6;         // 0..7
    int wr = w >> 2;             // 0..1 : which A half this wave consumes
    int wc = w & 3;              // 0..3 : which 64-col B strip
    int l31 = lane & 31;
    int kb  = (lane >> 5) * 32;  // k-byte base within a 64-k step

    // staging source: thread covers row (tid>>3) of each 64-row chunk,
    // 16B at pre-swizzled col ((tid&7) ^ ((tid>>3)&7))*16
    int scolb = ((tid & 7) ^ ((tid >> 3) & 7)) * 16;
    const char* gAr = (const char*)Xq + (size_t)(ntile * BM + (tid >> 3)) * 4096 + scolb;
    const char* gBr = (const char*)Wq + (size_t)(vtile * BN + (tid >> 3)) * 4096 + scolb;

    // swizzled ds_read offsets (within one operand buffer; add buf*32768)
    int offA[4][2];
    #pragma unroll
    for (int mi = 0; mi < 4; ++mi)
        #pragma unroll
        for (int ks = 0; ks < 2; ++ks) {
            int row = mi * 32 + l31;
            offA[mi][ks] = wr * 16384 + row * 128 + ((kb + ks * 64) ^ ((row & 7) << 4));
        }
    int offB[2][2];
    #pragma unroll
    for (int ni = 0; ni < 2; ++ni)
        #pragma unroll
        for (int ks = 0; ks < 2; ++ks) {
            int row = (wc & 1) * 64 + ni * 32 + l31;
            offB[ni][ks] = (wc >> 1) * 16384 + row * 128 + ((kb + ks * 64) ^ ((row & 7) << 4));
        }

    f32x16 acc[4][2];
    #pragma unroll
    for (int i = 0; i < 4; ++i)
        #pragma unroll
        for (int j = 0; j < 2; ++j)
            #pragma unroll
            for (int r = 0; r < 16; ++r)
                acc[i][j][r] = 0.f;

    i32x8 aLo[2][2], aHi[2][2], bF[2][2];

    // prologue: tile0 (8 loads) + {B0(1),B1(1),A0(1)} (6 loads in flight)
    STAGE_A(0, 0, 0); STAGE_A(0, 1, 0); STAGE_B(0, 0, 0); STAGE_B(0, 1, 0);
    STAGE_B(1, 0, 1); STAGE_B(1, 1, 1); STAGE_A(1, 0, 1);
    WAITV6();
    BAR();

    for (int t = 0; t < NKT; t += 2) {
        int t2 = (t + 2 < NKT) ? t + 2 : NKT - 1;   // clamped dummy re-stage at tail
        int t3 = (t + 3 < NKT) ? t + 3 : NKT - 1;

        // ---- ph0 (tile t, buf0): acc[0..1][0]
        RD_ALO(0); RD_BLO(0);
        STAGE_A(1, 1, t + 1);
        BAR();                     // compiler emits counted lgkm waits at uses
        SETP1(); MFMA_PH(aLo, 0, 0); SETP0();
        BAR();

        // ---- ph1: acc[0..1][1]
        RD_BHI(0);
        STAGE_B(0, 0, t2);
        BAR();
        SETP1(); MFMA_PH(aLo, 0, 1); SETP0();
        BAR();

        // ---- ph2: acc[2..3][1]
        RD_AHI(0);
        STAGE_B(0, 1, t2);
        BAR();
        SETP1(); MFMA_PH(aHi, 2, 1); SETP0();
        BAR();

        // ---- ph3: acc[2..3][0]; tile t+1 must land before ph4 reads
        STAGE_A(0, 0, t2);
        BAR();
        SETP1(); MFMA_PH(aHi, 2, 0); SETP0();
        WAITV6();
        BAR();

        // ---- ph4 (tile t+1, buf1): acc[0..1][0]
        RD_ALO(1); RD_BLO(1);
        STAGE_A(0, 1, t2);
        BAR();
        SETP1(); MFMA_PH(aLo, 0, 0); SETP0();
        BAR();

        // ---- ph5: acc[0..1][1]
        RD_BHI(1);
        STAGE_B(1, 0, t3);
        BAR();
        SETP1(); MFMA_PH(aLo, 0, 1); SETP0();
        BAR();

        // ---- ph6: acc[2..3][1]
        RD_AHI(1);
        STAGE_B(1, 1, t3);
        BAR();
        SETP1(); MFMA_PH(aHi, 2, 1); SETP0();
        BAR();

        // ---- ph7: acc[2..3][0]; tile t+2 must land before next ph0 reads
        STAGE_A(1, 0, t3);
        BAR();
        SETP1(); MFMA_PH(aHi, 2, 0); SETP0();
        WAITV6();
        BAR();
    }

    __syncthreads();   // full drain (vmcnt 0 + lgkm 0) before epilogue

    // Epilogue: per-row max and sumexp over this block's 256 cols.
    // 32x32 C/D layout: col = lane&31, row = (r&3) + 8*(r>>2) + 4*(lane>>5).
    // Unscale logits by 2^-6 (W was stored x64) -- exact power of two.
    const float inv64 = 0.015625f;
    #pragma unroll
    for (int mi = 0; mi < 4; ++mi) {
        #pragma unroll
        for (int r = 0; r < 16; ++r) {
            float v0 = acc[mi][0][r] * inv64;
            float v1 = acc[mi][1][r] * inv64;
            float mx = fmaxf(v0, v1);
            #pragma unroll
            for (int s = 1; s < 32; s <<= 1)
                mx = fmaxf(mx, __shfl_xor(mx, s, 64));
            float se = __expf(v0 - mx) + __expf(v1 - mx);
            #pragma unroll
            for (int s = 1; s < 32; s <<= 1)
                se += __shfl_xor(se, s, 64);
            if (l31 == 0) {
                int rloc = wr * 128 + mi * 32 + (r & 3) + 8 * (r >> 2) + 4 * (lane >> 5);
                red_m[wc][rloc] = mx;
                red_l[wc][rloc] = se;
            }
        }
    }
    __syncthreads();
    if (tid < BM) {
        float mm = red_m[0][tid], ll = red_l[0][tid];
        #pragma unroll
        for (int p = 1; p < 4; ++p) {
            float m2 = red_m[p][tid], l2 = red_l[p][tid];
            float m3 = fmaxf(mm, m2);
            ll = ll * __expf(mm - m3) + l2 * __expf(m2 - m3);
            mm = m3;
        }
        size_t idx = (size_t)vtile * N_ROWS + (size_t)(ntile * BM + tid);
        pm[idx] = mm;
        pl[idx] = ll;
    }
}

// tgt[row] = dot(x[row], W[y[row]]) in fp32 (exact vs reference)
__global__ void lmce_tgt_kernel(const float* __restrict__ X, const float* __restrict__ W,
                                const int* __restrict__ y, float* __restrict__ tgt)
{
    int row = blockIdx.x;
    int tid = threadIdx.x;
    int yv = y[row];
    float s = 0.f;
    if (yv >= 0 && yv < V_DIM) {
        const float* xr = X + (size_t)row * H_DIM;
        const float* wrow = W + (size_t)yv * H_DIM;
        #pragma unroll
        for (int j = 0; j < 4; ++j) {
            int idx = (tid + j * 256) * 4;
            f32x4 a = *(const f32x4*)(xr + idx);
            f32x4 b = *(const f32x4*)(wrow + idx);
            s += a.x * b.x + a.y * b.y + a.z * b.z + a.w * b.w;
        }
    }
    #pragma unroll
    for (int sh = 1; sh < 64; sh <<= 1) s += __shfl_xor(s, sh, 64);
    __shared__ float sred[4];
    if ((tid & 63) == 0) sred[tid >> 6] = s;
    __syncthreads();
    if (tid == 0) tgt[row] = sred[0] + sred[1] + sred[2] + sred[3];
}

// merge NT_V per-vtile (m,l) partials per row -> lse[row]
__global__ void lmce_lse_kernel(const float* __restrict__ pm, const float* __restrict__ pl,
                                float* __restrict__ lse)
{
    int tid = threadIdx.x;
    int row = blockIdx.x * 64 + (tid & 63);
    int part = tid >> 6;               // 0..3, each scans NT_V/4 = 125 vtiles
    const int per = NT_V / 4;
    float m = -INFINITY, l = 0.f;
    for (int vt = part * per; vt < (part + 1) * per; ++vt) {
        size_t idx = (size_t)vt * N_ROWS + row;
        float m2 = pm[idx], l2 = pl[idx];
        float mm = fmaxf(m, m2);
        l = l * __expf(m - mm) + l2 * __expf(m2 - mm);
        m = mm;
    }
    __shared__ float sm[4][64], sl[4][64];
    sm[part][tid & 63] = m;
    sl[part][tid & 63] = l;
    __syncthreads();
    if (tid < 64) {
        float M = sm[0][tid], L = sl[0][tid];
        #pragma unroll
        for (int p = 1; p < 4; ++p) {
            float m2 = sm[p][tid], l2 = sl[p][tid];
            float mm = fmaxf(M, m2);
            L = L * __expf(M - mm) + l2 * __expf(m2 - mm);
            M = mm;
        }
        lse[blockIdx.x * 64 + tid] = M + logf(L);
    }
}

__global__ void lmce_final_kernel(const float* __restrict__ lse, const float* __restrict__ tgt,
                                  const int* __restrict__ y, float* __restrict__ out)
{
    int tid = threadIdx.x;
    float s = 0.f, c = 0.f;
    for (int i = tid; i < N_ROWS; i += 256) {
        if (y[i] != IGNORE_INDEX) {
            s += lse[i] - tgt[i];
            c += 1.f;
        }
    }
    #pragma unroll
    for (int sh = 1; sh < 64; sh <<= 1) {
        s += __shfl_xor(s, sh, 64);
        c += __shfl_xor(c, sh, 64);
    }
    __shared__ float ss[4], cc[4];
    if ((tid & 63) == 0) { ss[tid >> 6] = s; cc[tid >> 6] = c; }
    __syncthreads();
    if (tid == 0) {
        float S = ss[0] + ss[1] + ss[2] + ss[3];
        float C = cc[0] + cc[1] + cc[2] + cc[3];
        out[0] = S / fmaxf(C, 1.f);
    }
}

extern "C" void kernel_launch(void* const* d_in, const int* in_sizes, int n_in,
                              void* d_out, int out_size, void* d_ws, size_t ws_size,
                              hipStream_t stream)
{
    const float* X = (const float*)d_in[0];   // [4096, 4096] fp32
    const int*   y = (const int*)d_in[1];     // [4096] labels
    const float* W = (const float*)d_in[2];   // [128000, 4096] fp32
    float* out = (float*)d_out;

    char* ws = (char*)d_ws;
    const size_t OFF_PL  = 16384000;
    const size_t OFF_TGT = 32768000;
    const size_t OFF_LSE = 32784384;
    const size_t OFF_XQ  = 32800768;                 // 16 MB fp8 X
    const size_t OFF_WQ  = OFF_XQ + 16777216;        // 512 MB fp8 W (x64 scaled)

    float* pm  = (float*)ws;
    float* pl  = (float*)(ws + OFF_PL);
    float* tgt = (float*)(ws + OFF_TGT);
    float* lse = (float*)(ws + OFF_LSE);
    unsigned char* Xq = (unsigned char*)(ws + OFF_XQ);
    unsigned char* Wq = (unsigned char*)(ws + OFF_WQ);

    cvt_f32_fp8_kernel<<<4096, 256, 0, stream>>>(W, Wq, (size_t)V_DIM * H_DIM, 64.0f);
    cvt_f32_fp8_kernel<<<512, 256, 0, stream>>>(X, Xq, (size_t)N_ROWS * H_DIM, 1.0f);
    lmce_gemm256_kernel<<<NT_N * NT_V, 512, 0, stream>>>(Xq, Wq, pm, pl);
    lmce_tgt_kernel<<<N_ROWS, 256, 0, stream>>>(X, W, y, tgt);
    lmce_lse_kernel<<<N_ROWS / 64, 256, 0, stream>>>(pm, pl, lse);
    lmce_final_kernel<<<1, 256, 0, stream>>>(lse, tgt, y, out);
}